// Round 6
// baseline (2365.981 us; speedup 1.0000x reference)
//
#include <hip/hip_runtime.h>

#define NB  30
#define BG  2048
#define EPG 240
#define NEg (BG*EPG)

__device__ __forceinline__ int ldidx(const void* p, long long i, int i64) {
    return i64 ? (int)((const long long*)p)[i] : ((const int*)p)[i];
}

// Probe: flags[0] = indices are int64; flags[1] = semantic/batch pointers swapped.
__global__ void probe_kernel(const void* edge, const void* semA, int* flags)
{
    if (threadIdx.x == 0) {
        const int* e32 = (const int*)edge;
        int zc = 0;
        for (int j = 1; j <= 31; j += 2) if (e32[j] == 0) zc++;
        const int i64 = (zc == 16) ? 1 : 0;
        flags[0] = i64;
        const int a = ldidx(semA, 61439, i64);   // semantic<=10, batch last=2047
        flags[1] = (a > 10) ? 1 : 0;
    }
}

// One block per graph. Thread = output channel d (0..255).
// h[n*512 + 0..255] = h[n]; h[n*512 + 256..511] = scratch (enc_geo, then mean).
__global__ __launch_bounds__(256, 2) void fused_kernel(
    const float* __restrict__ geometry,
    const void* __restrict__ semA, const void* __restrict__ semB,
    const void* __restrict__ edge_index,
    const float* __restrict__ W_geo, const float* __restrict__ b_geo,
    const float* __restrict__ emb,
    const float* __restrict__ W_lot, const float* __restrict__ b_lot,
    const float* __restrict__ Wmp1, const float* __restrict__ bmp1,
    const float* __restrict__ Wmp2, const float* __restrict__ bmp2,
    const float* __restrict__ Wmp3, const float* __restrict__ bmp3,
    const float* __restrict__ Wagg, const float* __restrict__ bagg,
    const float* __restrict__ Wmu,  const float* __restrict__ bmu,
    const float* __restrict__ Wvar, const float* __restrict__ bvar,
    float* __restrict__ out, const int* __restrict__ flags)
{
    __shared__ float h[NB * 512];        // 60 KB
    __shared__ float emb_l[11 * 256];    // 11 KB
    __shared__ float g_l[4 * 256];       // 4 KB
    __shared__ float lat[256];
    __shared__ float geo_l[NB * 5];
    __shared__ int   sem_l[NB];
    __shared__ int   csr_src[EPG];
    __shared__ int   rowstart[NB + 1];
    __shared__ int   e_src[EPG], e_dst[EPG];

    const int tid = threadIdx.x;
    const int g   = blockIdx.x;
    const int d   = tid;

    const int i64  = flags[0];
    const void* semantic = flags[1] ? semB : semA;

    // ---- stage inputs ----
    if (tid < EPG) {
        const long long e = (long long)g*EPG + tid;
        e_src[tid] = ldidx(edge_index, e,                  i64) - g*NB;  // row 0 = src
        e_dst[tid] = ldidx(edge_index, (long long)NEg + e, i64) - g*NB;  // row 1 = dst
    }
    if (tid < NB*5) geo_l[tid] = geometry[g*NB*5 + tid];
    if (tid < NB)   sem_l[tid] = ldidx(semantic, g*NB + tid, i64);
    for (int i = tid; i < 11*256; i += 256) emb_l[i] = emb[i];
    __syncthreads();

    // ---- CSR (incoming edges per dst), serial on thread 0 ----
    if (tid == 0) {
        int cnt[NB], fill[NB];
        for (int n = 0; n < NB; ++n) cnt[n] = 0;
        for (int e = 0; e < EPG; ++e) cnt[e_dst[e]]++;
        int a = 0;
        for (int n = 0; n < NB; ++n) { rowstart[n] = a; fill[n] = a; a += cnt[n]; }
        rowstart[NB] = a;
        for (int e = 0; e < EPG; ++e) csr_src[fill[e_dst[e]]++] = e_src[e];
    }
    // ---- enc_geo[n][k] = b_geo[k] + geo[n]·W_geo[:,k] (into scratch) ----
    for (int i = tid; i < NB*256; i += 256) {
        const int n = i >> 8, k = i & 255;
        float a = b_geo[k];
        #pragma unroll
        for (int p = 0; p < 5; ++p)
            a = fmaf(geo_l[n*5 + p], W_geo[p*256 + k], a);
        h[n*512 + 256 + k] = a;
    }
    __syncthreads();

    int sems[NB];
    #pragma unroll
    for (int n = 0; n < NB; ++n) sems[n] = sem_l[n];

    // ---- encoder ----
    float acc[NB];
    #pragma unroll
    for (int n = 0; n < NB; ++n)
        acc[n] = b_lot[d] + W_lot[(512 + n)*256 + d];       // x_pos one-hot
    for (int k = 0; k < 256; ++k) {
        const float w1 = W_lot[k*256 + d];
        const float w2 = W_lot[(256 + k)*256 + d];
        #pragma unroll
        for (int n = 0; n < NB; ++n) {
            acc[n] = fmaf(h[n*512 + 256 + k], w1, acc[n]);
            acc[n] = fmaf(emb_l[sems[n]*256 + k], w2, acc[n]);
        }
    }
    {
        float gmax = 0.f;
        #pragma unroll
        for (int n = 0; n < NB; ++n) {
            const float v = fmaxf(acc[n], 0.f);
            h[n*512 + d] = v;
            gmax = fmaxf(gmax, v);
        }
        g_l[d] = gmax;                   // g0
    }
    __syncthreads();

    // ---- 3 message-passing rounds ----
    const float* Wr[3] = { Wmp1, Wmp2, Wmp3 };
    const float* br[3] = { bmp1, bmp2, bmp3 };
    for (int r = 0; r < 3; ++r) {
        for (int n = 0; n < NB; ++n) {
            const int lo = rowstart[n], hi = rowstart[n+1];
            float a = 0.f;
            for (int j = lo; j < hi; ++j)
                a += h[csr_src[j]*512 + d];
            h[n*512 + 256 + d] = (hi > lo) ? a / (float)(hi - lo) : 0.f;
        }
        __syncthreads();

        const float* __restrict__ W = Wr[r];
        const float bb = br[r][d];
        #pragma unroll
        for (int n = 0; n < NB; ++n) acc[n] = bb;
        for (int k = 0; k < 512; ++k) {
            const float w = W[k*256 + d];
            #pragma unroll
            for (int n = 0; n < NB; ++n)
                acc[n] = fmaf(h[n*512 + k], w, acc[n]);
        }
        __syncthreads();

        float gmax = 0.f;
        #pragma unroll
        for (int n = 0; n < NB; ++n) {
            const float v = (rowstart[n+1] > rowstart[n]) ? fmaxf(acc[n], 0.f) : 0.f;
            h[n*512 + d] = v;
            gmax = fmaxf(gmax, v);
        }
        g_l[(r+1)*256 + d] = gmax;
        __syncthreads();
    }

    // ---- heads ----
    float a1 = bagg[d];
    for (int k = 0; k < 1024; ++k)
        a1 = fmaf(g_l[k], Wagg[k*256 + d], a1);
    lat[d] = a1;
    __syncthreads();

    float m = bmu[d], vv = bvar[d];
    for (int k = 0; k < 256; ++k) {
        const float l = lat[k];
        m  = fmaf(l, Wmu[k*256 + d],  m);
        vv = fmaf(l, Wvar[k*256 + d], vv);
    }
    // FP32 output: reference returns float32 -> d_out is float* per harness rule.
    out[(size_t)g*256 + d]                        = m;
    out[(size_t)BG*256 + (size_t)g*256 + d]       = vv;
}

extern "C" void kernel_launch(void* const* d_in, const int* in_sizes, int n_in,
                              void* d_out, int out_size, void* d_ws, size_t ws_size,
                              hipStream_t stream)
{
    const float* geometry  = (const float*)d_in[0];
    const void*  semantic  = d_in[1];
    const void*  batch     = d_in[3];
    const void*  edge_ix   = d_in[2];
    const float* W_geo = (const float*)d_in[4];
    const float* b_geo = (const float*)d_in[5];
    const float* emb   = (const float*)d_in[6];
    const float* W_lot = (const float*)d_in[7];
    const float* b_lot = (const float*)d_in[8];
    const float* Wmp1  = (const float*)d_in[9];
    const float* bmp1  = (const float*)d_in[10];
    const float* Wmp2  = (const float*)d_in[11];
    const float* bmp2  = (const float*)d_in[12];
    const float* Wmp3  = (const float*)d_in[13];
    const float* bmp3  = (const float*)d_in[14];
    const float* Wagg  = (const float*)d_in[15];
    const float* bagg  = (const float*)d_in[16];
    const float* Wmu   = (const float*)d_in[17];
    const float* bmu   = (const float*)d_in[18];
    const float* Wvar  = (const float*)d_in[19];
    const float* bvar  = (const float*)d_in[20];

    int* flags = (int*)d_ws;
    probe_kernel<<<1, 64, 0, stream>>>(edge_ix, semantic, flags);

    fused_kernel<<<BG, 256, 0, stream>>>(
        geometry, semantic, batch, edge_ix,
        W_geo, b_geo, emb, W_lot, b_lot,
        Wmp1, bmp1, Wmp2, bmp2, Wmp3, bmp3,
        Wagg, bagg, Wmu, bmu, Wvar, bvar,
        (float*)d_out, flags);
}

// Round 7
// 412.775 us; speedup vs baseline: 5.7319x; 5.7319x over previous
//
#include <hip/hip_runtime.h>

typedef unsigned short u16;
typedef __attribute__((ext_vector_type(8))) short bf8;   // 8 bf16 (4 VGPRs)
typedef __attribute__((ext_vector_type(4))) float f4;    // MFMA C/D frag
typedef __attribute__((ext_vector_type(4))) int i4;

#define NB  30
#define BG  2048
#define EPG 240
#define NEg (BG*EPG)
#define SA  520     // A row stride (bf16 elems): 512 + 8 pad -> 2-way banks
#define SS  40      // S row stride
#define SL  264     // latent row stride (heads)

// workspace offsets (bytes)
#define WOFF_WT    0                         // W_mp^T bf16 [3][256][512] = 786432
#define WOFF_WAGG  786432                    // W_agg^T bf16 [256][1024] = 524288
#define WOFF_WMU   (786432+524288)           // [256][256] bf16 = 131072
#define WOFF_WVAR  (786432+524288+131072)    // 131072
#define WOFF_TAB   (786432+524288+262144)    // tables fp32: 12032 floats = 48128 B
#define WOFF_G     (WOFF_TAB + 48128)        // g bf16 [2048][1024] = 4194304
#define WOFF_FLAG  (WOFF_G + 4194304)        // 2 ints

// tables layout (float idx): M5[5*256]@0, c[256]@1280, T_sem[11*256]@1536, T_pos[30*256]@4352

__device__ __forceinline__ float us2f(u16 u) {
    union { unsigned int i; float f; } v; v.i = ((unsigned int)u) << 16; return v.f;
}
__device__ __forceinline__ u16 f2us(float f) {
    union { float f; unsigned int u; } v; v.f = f;
    unsigned int u = v.u;
    return (u16)((u + 0x7FFFu + ((u >> 16) & 1u)) >> 16);   // RNE
}
__device__ __forceinline__ int ldidx(const void* p, long long i, int i64) {
    return i64 ? (int)((const long long*)p)[i] : ((const int*)p)[i];
}

__global__ void probe_kernel(const void* edge, const void* semA, int* flags)
{
    if (threadIdx.x == 0) {
        const int* e32 = (const int*)edge;
        int zc = 0;
        for (int j = 1; j <= 31; j += 2) if (e32[j] == 0) zc++;
        const int i64 = (zc == 16) ? 1 : 0;
        flags[0] = i64;
        const int a = ldidx(semA, 61439, i64);   // semantic<=10, batch last=2047
        flags[1] = (a > 10) ? 1 : 0;
    }
}

// ---------------------------------------------------------------------------
// Prep: transpose+bf16 weights, build exact fp32 encoder tables.
// ---------------------------------------------------------------------------
__global__ __launch_bounds__(256) void prep_kernel(
    const float* __restrict__ Wmp1, const float* __restrict__ Wmp2,
    const float* __restrict__ Wmp3, const float* __restrict__ Wagg,
    const float* __restrict__ Wmu,  const float* __restrict__ Wvar,
    const float* __restrict__ W_geo, const float* __restrict__ b_geo,
    const float* __restrict__ emb,   const float* __restrict__ W_lot,
    const float* __restrict__ b_lot, char* __restrict__ ws)
{
    const int t = threadIdx.x;
    const int b = blockIdx.x;
    if (b < 768) {
        const int r = b >> 8, n = b & 255;
        const float* W = (r == 0) ? Wmp1 : ((r == 1) ? Wmp2 : Wmp3);
        u16* Wt = (u16*)(ws + WOFF_WT) + (r*256 + n)*512;
        for (int k = t; k < 512; k += 256) Wt[k] = f2us(W[k*256 + n]);
    } else if (b < 1024) {
        const int n = b - 768;
        u16* Wt = (u16*)(ws + WOFF_WAGG) + n*1024;
        for (int k = t; k < 1024; k += 256) Wt[k] = f2us(Wagg[k*256 + n]);
    } else if (b < 1280) {
        const int n = b - 1024;
        u16* Wtm = (u16*)(ws + WOFF_WMU)  + n*256;
        u16* Wtv = (u16*)(ws + WOFF_WVAR) + n*256;
        Wtm[t] = f2us(Wmu[t*256 + n]);
        Wtv[t] = f2us(Wvar[t*256 + n]);
    } else {
        float* tab = (float*)(ws + WOFF_TAB);
        const int d = t, b2 = b - 1280;
        if (b2 < 5) {
            float a = 0.f;
            for (int k = 0; k < 256; ++k)
                a = fmaf(W_geo[b2*256 + k], W_lot[k*256 + d], a);
            tab[b2*256 + d] = a;
        } else if (b2 < 16) {
            const int s = b2 - 5;
            float a = 0.f;
            for (int k = 0; k < 256; ++k)
                a = fmaf(emb[s*256 + k], W_lot[(256 + k)*256 + d], a);
            tab[1536 + s*256 + d] = a;
        } else {
            float a = b_lot[d];
            for (int k = 0; k < 256; ++k)
                a = fmaf(b_geo[k], W_lot[k*256 + d], a);
            tab[1280 + d] = a;
            for (int p = 0; p < NB; ++p)
                tab[4352 + p*256 + d] = W_lot[(512 + p)*256 + d];
        }
    }
}

// ---------------------------------------------------------------------------
// Graph kernel: one block per graph, 4 waves. MFMA 16x16x32 bf16.
// A[32][512] bf16 hi/lo planes in LDS: cols 0-255 = h, 256-511 = mean.
// ---------------------------------------------------------------------------
__global__ __launch_bounds__(256) void graph_kernel(
    const float* __restrict__ geometry,
    const void* __restrict__ semA, const void* __restrict__ semB,
    const void* __restrict__ edge_index,
    const float* __restrict__ bmp1, const float* __restrict__ bmp2,
    const float* __restrict__ bmp3,
    const char* __restrict__ ws, u16* __restrict__ G,
    const int* __restrict__ flags)
{
    __shared__ __align__(16) short Ahi[32*SA];   // 33280 B
    __shared__ __align__(16) short Alo[32*SA];   // 33280 B
    __shared__ __align__(16) short Shi[32*SS];   // 2560 B
    __shared__ __align__(16) short Slo[32*SS];   // 2560 B
    __shared__ int cntC[32*32];                  // 4096 B
    __shared__ int cntN[32];

    const int tid  = threadIdx.x;
    const int g    = blockIdx.x;
    const int wave = tid >> 6, lane = tid & 63;
    const int l16  = lane & 15, quad = lane >> 4;

    const int i64 = flags[0];
    const void* semantic = flags[1] ? semB : semA;
    const u16* WtAll = (const u16*)(ws + WOFF_WT);
    const float* tab = (const float*)(ws + WOFF_TAB);

    // ---- zero LDS ----
    {
        i4 z = {0, 0, 0, 0};
        i4* pa = (i4*)Ahi; i4* pb = (i4*)Alo;
        for (int i = tid; i < 2080; i += 256) { pa[i] = z; pb[i] = z; }
        i4* ps = (i4*)Shi; i4* pt = (i4*)Slo;
        if (tid < 160) { ps[tid] = z; pt[tid] = z; }
        for (int i = tid; i < 1024; i += 256) cntC[i] = 0;
        if (tid < 32) cntN[tid] = 0;
    }
    __syncthreads();

    // ---- edge counts (atomic) ----
    if (tid < EPG) {
        const long long e = (long long)g*EPG + tid;
        const int s  = ldidx(edge_index, e,                  i64) - g*NB;
        const int dd = ldidx(edge_index, (long long)NEg + e, i64) - g*NB;
        atomicAdd(&cntC[dd*32 + s], 1);
        atomicAdd(&cntN[dd], 1);
    }

    // ---- encoder via exact tables; thread = col d ----
    {
        const int d = tid;
        const float m0 = tab[0*256+d], m1 = tab[1*256+d], m2 = tab[2*256+d],
                    m3 = tab[3*256+d], m4 = tab[4*256+d];
        const float cD = tab[1280 + d];
        float gmax = 0.f;
        for (int n = 0; n < NB; ++n) {
            const float* gr = geometry + ((size_t)g*NB + n)*5;
            const int s = ldidx(semantic, g*NB + n, i64);
            float a = cD + tab[1536 + s*256 + d] + tab[4352 + n*256 + d];
            a = fmaf(gr[0], m0, a); a = fmaf(gr[1], m1, a); a = fmaf(gr[2], m2, a);
            a = fmaf(gr[3], m3, a); a = fmaf(gr[4], m4, a);
            const float v = fmaxf(a, 0.f);
            const u16 hi = f2us(v);
            Ahi[n*SA + d] = (short)hi;
            Alo[n*SA + d] = (short)f2us(v - us2f(hi));
            gmax = fmaxf(gmax, v);
        }
        G[(size_t)g*1024 + d] = f2us(gmax);   // g0
    }
    __syncthreads();

    // ---- build S = cnt_nm / cnt_n, split hi/lo ----
    for (int i = tid; i < 960; i += 256) {
        const int n = i >> 5, m = i & 31;
        const int c = cntC[n*32 + m], cn = cntN[n];
        const float v = (cn > 0) ? (float)c / (float)cn : 0.f;
        const u16 hi = f2us(v);
        Shi[n*SS + m] = (short)hi;
        Slo[n*SS + m] = (short)f2us(v - us2f(hi));
    }
    __syncthreads();

    // ---- 3 message-passing rounds ----
    for (int r = 0; r < 3; ++r) {
        // mean = S @ h  (K=32, one MFMA step; 3 MFMAs for split precision)
        {
            bf8 sh[2], sl[2];
            #pragma unroll
            for (int mt = 0; mt < 2; ++mt) {
                sh[mt] = *(const bf8*)&Shi[(mt*16 + l16)*SS + quad*8];
                sl[mt] = *(const bf8*)&Slo[(mt*16 + l16)*SS + quad*8];
            }
            #pragma unroll
            for (int nt = 0; nt < 4; ++nt) {
                const int ncol = wave*64 + nt*16 + l16;
                bf8 bh, bl;
                #pragma unroll
                for (int j = 0; j < 8; ++j) {
                    bh[j] = Ahi[(quad*8 + j)*SA + ncol];
                    bl[j] = Alo[(quad*8 + j)*SA + ncol];
                }
                #pragma unroll
                for (int mt = 0; mt < 2; ++mt) {
                    f4 acc = {0.f, 0.f, 0.f, 0.f};
                    acc = __builtin_amdgcn_mfma_f32_16x16x32_bf16(sh[mt], bh, acc, 0, 0, 0);
                    acc = __builtin_amdgcn_mfma_f32_16x16x32_bf16(sh[mt], bl, acc, 0, 0, 0);
                    acc = __builtin_amdgcn_mfma_f32_16x16x32_bf16(sl[mt], bh, acc, 0, 0, 0);
                    #pragma unroll
                    for (int i = 0; i < 4; ++i) {
                        const int row = mt*16 + quad*4 + i;
                        const float v = acc[i];
                        const u16 hi = f2us(v);
                        Ahi[row*SA + 256 + ncol] = (short)hi;
                        Alo[row*SA + 256 + ncol] = (short)f2us(v - us2f(hi));
                    }
                }
            }
        }
        __syncthreads();

        // main GEMM: C[32][256] = A[32][512] @ W_r
        f4 acc[2][4];
        #pragma unroll
        for (int mt = 0; mt < 2; ++mt)
            #pragma unroll
            for (int nt = 0; nt < 4; ++nt) acc[mt][nt] = (f4){0.f, 0.f, 0.f, 0.f};

        const u16* Wt = WtAll + ((size_t)r*256 + wave*64)*512;
        for (int kt = 0; kt < 16; ++kt) {
            bf8 ah[2], al[2];
            #pragma unroll
            for (int mt = 0; mt < 2; ++mt) {
                ah[mt] = *(const bf8*)&Ahi[(mt*16 + l16)*SA + kt*32 + quad*8];
                al[mt] = *(const bf8*)&Alo[(mt*16 + l16)*SA + kt*32 + quad*8];
            }
            #pragma unroll
            for (int nt = 0; nt < 4; ++nt) {
                const bf8 b = *(const bf8*)&Wt[(nt*16 + l16)*512 + kt*32 + quad*8];
                #pragma unroll
                for (int mt = 0; mt < 2; ++mt) {
                    acc[mt][nt] = __builtin_amdgcn_mfma_f32_16x16x32_bf16(ah[mt], b, acc[mt][nt], 0, 0, 0);
                    acc[mt][nt] = __builtin_amdgcn_mfma_f32_16x16x32_bf16(al[mt], b, acc[mt][nt], 0, 0, 0);
                }
            }
        }
        __syncthreads();   // all A reads complete before epilogue overwrites

        // epilogue: +bias, relu, masks, write h hi/lo, column max -> g
        const float* br = (r == 0) ? bmp1 : ((r == 1) ? bmp2 : bmp3);
        #pragma unroll
        for (int nt = 0; nt < 4; ++nt) {
            const int col = wave*64 + nt*16 + l16;
            const float bias = br[col];
            float cmax = 0.f;
            #pragma unroll
            for (int mt = 0; mt < 2; ++mt) {
                #pragma unroll
                for (int i = 0; i < 4; ++i) {
                    const int row = mt*16 + quad*4 + i;
                    float v = fmaxf(acc[mt][nt][i] + bias, 0.f);
                    if (row >= NB || cntN[row] == 0) v = 0.f;
                    const u16 hi = f2us(v);
                    Ahi[row*SA + col] = (short)hi;
                    Alo[row*SA + col] = (short)f2us(v - us2f(hi));
                    cmax = fmaxf(cmax, v);
                }
            }
            cmax = fmaxf(cmax, __shfl_xor(cmax, 16));
            cmax = fmaxf(cmax, __shfl_xor(cmax, 32));
            if (quad == 0)
                G[(size_t)g*1024 + (r+1)*256 + col] = f2us(cmax);
        }
        __syncthreads();
    }
}

// ---------------------------------------------------------------------------
// Heads: 64 blocks x 32 graphs. latent = G@Wagg+b; mu/lv = latent@{Wmu,Wvar}+b.
// ---------------------------------------------------------------------------
__global__ __launch_bounds__(256) void head_kernel(
    const char* __restrict__ ws, const u16* __restrict__ G,
    const float* __restrict__ bagg, const float* __restrict__ bmu,
    const float* __restrict__ bvar, float* __restrict__ out)
{
    __shared__ __align__(16) short Lhi[32*SL];
    __shared__ __align__(16) short Llo[32*SL];

    const int tid  = threadIdx.x;
    const int wave = tid >> 6, lane = tid & 63;
    const int l16  = lane & 15, quad = lane >> 4;
    const int g0   = blockIdx.x * 32;

    const u16* WtA = (const u16*)(ws + WOFF_WAGG);
    const u16* WtM = (const u16*)(ws + WOFF_WMU);
    const u16* WtV = (const u16*)(ws + WOFF_WVAR);

    // GEMM1: latent[32][256] = G[32][1024] @ Wagg
    f4 acc[2][4];
    #pragma unroll
    for (int mt = 0; mt < 2; ++mt)
        #pragma unroll
        for (int nt = 0; nt < 4; ++nt) acc[mt][nt] = (f4){0.f, 0.f, 0.f, 0.f};

    for (int kt = 0; kt < 32; ++kt) {
        bf8 ah[2];
        #pragma unroll
        for (int mt = 0; mt < 2; ++mt)
            ah[mt] = *(const bf8*)&G[(size_t)(g0 + mt*16 + l16)*1024 + kt*32 + quad*8];
        #pragma unroll
        for (int nt = 0; nt < 4; ++nt) {
            const bf8 b = *(const bf8*)&WtA[(size_t)(wave*64 + nt*16 + l16)*1024 + kt*32 + quad*8];
            #pragma unroll
            for (int mt = 0; mt < 2; ++mt)
                acc[mt][nt] = __builtin_amdgcn_mfma_f32_16x16x32_bf16(ah[mt], b, acc[mt][nt], 0, 0, 0);
        }
    }
    #pragma unroll
    for (int nt = 0; nt < 4; ++nt) {
        const int col = wave*64 + nt*16 + l16;
        const float bias = bagg[col];
        #pragma unroll
        for (int mt = 0; mt < 2; ++mt)
            #pragma unroll
            for (int i = 0; i < 4; ++i) {
                const int row = mt*16 + quad*4 + i;
                const float v = acc[mt][nt][i] + bias;
                const u16 hi = f2us(v);
                Lhi[row*SL + col] = (short)hi;
                Llo[row*SL + col] = (short)f2us(v - us2f(hi));
            }
    }
    __syncthreads();

    // GEMM2: mu / log_var
    f4 am[2][4], av[2][4];
    #pragma unroll
    for (int mt = 0; mt < 2; ++mt)
        #pragma unroll
        for (int nt = 0; nt < 4; ++nt) {
            am[mt][nt] = (f4){0.f, 0.f, 0.f, 0.f};
            av[mt][nt] = (f4){0.f, 0.f, 0.f, 0.f};
        }
    for (int kt = 0; kt < 8; ++kt) {
        bf8 ah[2], al[2];
        #pragma unroll
        for (int mt = 0; mt < 2; ++mt) {
            ah[mt] = *(const bf8*)&Lhi[(mt*16 + l16)*SL + kt*32 + quad*8];
            al[mt] = *(const bf8*)&Llo[(mt*16 + l16)*SL + kt*32 + quad*8];
        }
        #pragma unroll
        for (int nt = 0; nt < 4; ++nt) {
            const bf8 bm_ = *(const bf8*)&WtM[(wave*64 + nt*16 + l16)*256 + kt*32 + quad*8];
            const bf8 bv_ = *(const bf8*)&WtV[(wave*64 + nt*16 + l16)*256 + kt*32 + quad*8];
            #pragma unroll
            for (int mt = 0; mt < 2; ++mt) {
                am[mt][nt] = __builtin_amdgcn_mfma_f32_16x16x32_bf16(ah[mt], bm_, am[mt][nt], 0, 0, 0);
                am[mt][nt] = __builtin_amdgcn_mfma_f32_16x16x32_bf16(al[mt], bm_, am[mt][nt], 0, 0, 0);
                av[mt][nt] = __builtin_amdgcn_mfma_f32_16x16x32_bf16(ah[mt], bv_, av[mt][nt], 0, 0, 0);
                av[mt][nt] = __builtin_amdgcn_mfma_f32_16x16x32_bf16(al[mt], bv_, av[mt][nt], 0, 0, 0);
            }
        }
    }
    #pragma unroll
    for (int nt = 0; nt < 4; ++nt) {
        const int col = wave*64 + nt*16 + l16;
        const float b1 = bmu[col], b2 = bvar[col];
        #pragma unroll
        for (int mt = 0; mt < 2; ++mt)
            #pragma unroll
            for (int i = 0; i < 4; ++i) {
                const int row = g0 + mt*16 + quad*4 + i;
                out[(size_t)row*256 + col]          = am[mt][nt][i] + b1;
                out[524288 + (size_t)row*256 + col] = av[mt][nt][i] + b2;
            }
    }
}

extern "C" void kernel_launch(void* const* d_in, const int* in_sizes, int n_in,
                              void* d_out, int out_size, void* d_ws, size_t ws_size,
                              hipStream_t stream)
{
    const float* geometry  = (const float*)d_in[0];
    const void*  semantic  = d_in[1];
    const void*  edge_ix   = d_in[2];
    const void*  batch     = d_in[3];
    const float* W_geo = (const float*)d_in[4];
    const float* b_geo = (const float*)d_in[5];
    const float* emb   = (const float*)d_in[6];
    const float* W_lot = (const float*)d_in[7];
    const float* b_lot = (const float*)d_in[8];
    const float* Wmp1  = (const float*)d_in[9];
    const float* bmp1  = (const float*)d_in[10];
    const float* Wmp2  = (const float*)d_in[11];
    const float* bmp2  = (const float*)d_in[12];
    const float* Wmp3  = (const float*)d_in[13];
    const float* bmp3  = (const float*)d_in[14];
    const float* Wagg  = (const float*)d_in[15];
    const float* bagg  = (const float*)d_in[16];
    const float* Wmu   = (const float*)d_in[17];
    const float* bmu   = (const float*)d_in[18];
    const float* Wvar  = (const float*)d_in[19];
    const float* bvar  = (const float*)d_in[20];

    char* ws    = (char*)d_ws;
    int*  flags = (int*)(ws + WOFF_FLAG);
    u16*  G     = (u16*)(ws + WOFF_G);

    probe_kernel<<<1, 64, 0, stream>>>(edge_ix, semantic, flags);
    prep_kernel<<<1297, 256, 0, stream>>>(Wmp1, Wmp2, Wmp3, Wagg, Wmu, Wvar,
                                          W_geo, b_geo, emb, W_lot, b_lot, ws);
    graph_kernel<<<BG, 256, 0, stream>>>(geometry, semantic, batch, edge_ix,
                                         bmp1, bmp2, bmp3, ws, G, flags);
    head_kernel<<<64, 256, 0, stream>>>(ws, G, bagg, bmu, bvar, (float*)d_out);
}

// Round 8
// 379.495 us; speedup vs baseline: 6.2345x; 1.0877x over previous
//
#include <hip/hip_runtime.h>

typedef unsigned short u16;
typedef __attribute__((ext_vector_type(8))) short bf8;   // 8 bf16 (4 VGPRs)
typedef __attribute__((ext_vector_type(4))) float f4;    // MFMA C/D frag
typedef __attribute__((ext_vector_type(4))) int i4;

#define NB  30
#define BG  2048
#define EPG 240
#define NEg (BG*EPG)
#define SA  536     // A row stride (shorts): 268 dw ≡ 12 mod 32 -> uniform bank starts
#define SS  40      // S row stride
#define SL  264     // latent row stride (heads)

// workspace offsets (bytes)
#define WOFF_WT    0                         // W_mp^T bf16 [3][256][512]
#define WOFF_WAGG  786432                    // W_agg^T bf16 [256][1024]
#define WOFF_WMU   (786432+524288)           // [256][256] bf16
#define WOFF_WVAR  (786432+524288+131072)
#define WOFF_TAB   (786432+524288+262144)    // fp32 tables: 12032 floats
#define WOFF_G     (WOFF_TAB + 48128)        // g bf16 [2048][1024]
#define WOFF_FLAG  (WOFF_G + 4194304)        // 2 ints

__device__ __forceinline__ float us2f(u16 u) {
    union { unsigned int i; float f; } v; v.i = ((unsigned int)u) << 16; return v.f;
}
__device__ __forceinline__ u16 f2us(float f) {
    union { float f; unsigned int u; } v; v.f = f;
    unsigned int u = v.u;
    return (u16)((u + 0x7FFFu + ((u >> 16) & 1u)) >> 16);   // RNE
}
__device__ __forceinline__ int ldidx(const void* p, long long i, int i64) {
    return i64 ? (int)((const long long*)p)[i] : ((const int*)p)[i];
}

// ---------------------------------------------------------------------------
// Prep (210 blocks): coalesced 64x64 tile transposes -> bf16, fp32 encoder
// tables, and the dtype probe (block 209).
// ---------------------------------------------------------------------------
__global__ __launch_bounds__(256) void prep_kernel(
    const float* __restrict__ Wmp1, const float* __restrict__ Wmp2,
    const float* __restrict__ Wmp3, const float* __restrict__ Wagg,
    const float* __restrict__ Wmu,  const float* __restrict__ Wvar,
    const float* __restrict__ W_geo, const float* __restrict__ b_geo,
    const float* __restrict__ emb,   const float* __restrict__ W_lot,
    const float* __restrict__ b_lot,
    const void* __restrict__ edge,  const void* __restrict__ semA,
    char* __restrict__ ws, int* __restrict__ flags)
{
    const int t = threadIdx.x;
    const int b = blockIdx.x;

    if (b == 209) {                    // probe
        if (t == 0) {
            const int* e32 = (const int*)edge;
            int zc = 0;
            for (int j = 1; j <= 31; j += 2) if (e32[j] == 0) zc++;
            const int i64 = (zc == 16) ? 1 : 0;
            flags[0] = i64;
            const int a = ldidx(semA, 61439, i64);   // semantic<=10, batch last=2047
            flags[1] = (a > 10) ? 1 : 0;
        }
        return;
    }

    if (b >= 192) {                    // tables (exact fp32 algebra)
        float* tab = (float*)(ws + WOFF_TAB);
        const int d = t, b2 = b - 192;
        if (b2 < 5) {
            float a = 0.f;
            for (int k = 0; k < 256; ++k)
                a = fmaf(W_geo[b2*256 + k], W_lot[k*256 + d], a);
            tab[b2*256 + d] = a;
        } else if (b2 < 16) {
            const int s = b2 - 5;
            float a = 0.f;
            for (int k = 0; k < 256; ++k)
                a = fmaf(emb[s*256 + k], W_lot[(256 + k)*256 + d], a);
            tab[1536 + s*256 + d] = a;
        } else {
            float a = b_lot[d];
            for (int k = 0; k < 256; ++k)
                a = fmaf(b_geo[k], W_lot[k*256 + d], a);
            tab[1280 + d] = a;
            for (int p = 0; p < NB; ++p)
                tab[4352 + p*256 + d] = W_lot[(512 + p)*256 + d];
        }
        return;
    }

    // 64x64 tile transpose: W[K][256] fp32 -> Wt[256][K] bf16
    __shared__ short tile[64 * 65];
    const float* W; u16* Wt; int K, bk, bn;
    if (b < 96)       { const int r = b/32, tt = b%32;
                        W = (r==0)?Wmp1:((r==1)?Wmp2:Wmp3);
                        Wt = (u16*)(ws + WOFF_WT) + (size_t)r*256*512;
                        K = 512;  bk = tt/4;  bn = tt%4; }
    else if (b < 160) { const int tt = b-96;
                        W = Wagg; Wt = (u16*)(ws + WOFF_WAGG);
                        K = 1024; bk = tt/4;  bn = tt%4; }
    else if (b < 176) { const int tt = b-160;
                        W = Wmu;  Wt = (u16*)(ws + WOFF_WMU);
                        K = 256;  bk = tt/4;  bn = tt%4; }
    else              { const int tt = b-176;
                        W = Wvar; Wt = (u16*)(ws + WOFF_WVAR);
                        K = 256;  bk = tt/4;  bn = tt%4; }

    const int r = t >> 6, c = t & 63;
    const int k0 = bk*64, n0 = bn*64;
    #pragma unroll
    for (int i = 0; i < 16; ++i) {
        const int kk = r + i*4;
        tile[kk*65 + c] = (short)f2us(W[(size_t)(k0 + kk)*256 + n0 + c]);
    }
    __syncthreads();
    #pragma unroll
    for (int i = 0; i < 16; ++i) {
        const int nn = r + i*4;
        Wt[(size_t)(n0 + nn)*K + k0 + c] = (u16)tile[c*65 + nn];
    }
}

// ---------------------------------------------------------------------------
// Graph kernel: one block per graph, 4 waves. A = bf16 (single plane),
// S = exact hi/lo split. MFMA 16x16x32 bf16.
// ---------------------------------------------------------------------------
__global__ __launch_bounds__(256, 3) void graph_kernel(
    const float* __restrict__ geometry,
    const void* __restrict__ semA, const void* __restrict__ semB,
    const void* __restrict__ edge_index,
    const float* __restrict__ bmp1, const float* __restrict__ bmp2,
    const float* __restrict__ bmp3,
    const char* __restrict__ ws, u16* __restrict__ G,
    const int* __restrict__ flags)
{
    __shared__ __align__(16) short Ahi[32*SA];   // 34304 B
    __shared__ __align__(16) short Shi[32*SS];   // 2560 B
    __shared__ __align__(16) short Slo[32*SS];   // 2560 B
    __shared__ int cntC[32*32];                  // 4096 B
    __shared__ int cntN[32];

    const int tid  = threadIdx.x;
    const int g    = blockIdx.x;
    const int wave = tid >> 6, lane = tid & 63;
    const int l16  = lane & 15, quad = lane >> 4;

    const int i64 = flags[0];
    const void* semantic = flags[1] ? semB : semA;
    const u16* WtAll = (const u16*)(ws + WOFF_WT);
    const float* tab = (const float*)(ws + WOFF_TAB);

    // ---- zero LDS ----
    {
        i4 z = {0, 0, 0, 0};
        i4* pa = (i4*)Ahi;
        for (int i = tid; i < 32*SA/8; i += 256) pa[i] = z;
        i4* ps = (i4*)Shi; i4* pt = (i4*)Slo;
        if (tid < 160) { ps[tid] = z; pt[tid] = z; }
        for (int i = tid; i < 1024; i += 256) cntC[i] = 0;
        if (tid < 32) cntN[tid] = 0;
    }
    __syncthreads();

    // ---- edge counts ----
    if (tid < EPG) {
        const long long e = (long long)g*EPG + tid;
        const int s  = ldidx(edge_index, e,                  i64) - g*NB;
        const int dd = ldidx(edge_index, (long long)NEg + e, i64) - g*NB;
        atomicAdd(&cntC[dd*32 + s], 1);
        atomicAdd(&cntN[dd], 1);
    }

    // ---- encoder via exact tables; thread = col d ----
    {
        const int d = tid;
        const float m0 = tab[0*256+d], m1 = tab[1*256+d], m2 = tab[2*256+d],
                    m3 = tab[3*256+d], m4 = tab[4*256+d];
        const float cD = tab[1280 + d];
        float gmax = 0.f;
        for (int n = 0; n < NB; ++n) {
            const float* gr = geometry + ((size_t)g*NB + n)*5;
            const int s = ldidx(semantic, g*NB + n, i64);
            float a = cD + tab[1536 + s*256 + d] + tab[4352 + n*256 + d];
            a = fmaf(gr[0], m0, a); a = fmaf(gr[1], m1, a); a = fmaf(gr[2], m2, a);
            a = fmaf(gr[3], m3, a); a = fmaf(gr[4], m4, a);
            const float v = fmaxf(a, 0.f);
            Ahi[n*SA + d] = (short)f2us(v);
            gmax = fmaxf(gmax, v);
        }
        G[(size_t)g*1024 + d] = f2us(gmax);   // g0
    }
    __syncthreads();

    // ---- S = cnt_nm / cnt_n, exact hi/lo split ----
    for (int i = tid; i < 960; i += 256) {
        const int n = i >> 5, m = i & 31;
        const int c = cntC[n*32 + m], cn = cntN[n];
        const float v = (cn > 0) ? (float)c / (float)cn : 0.f;
        const u16 hi = f2us(v);
        Shi[n*SS + m] = (short)hi;
        Slo[n*SS + m] = (short)f2us(v - us2f(hi));
    }
    __syncthreads();

    // ---- 3 message-passing rounds ----
    for (int r = 0; r < 3; ++r) {
        // mean = S @ h  (K=32; 2 MFMAs: S split, h single-plane)
        {
            bf8 sh[2], sl[2];
            #pragma unroll
            for (int mt = 0; mt < 2; ++mt) {
                sh[mt] = *(const bf8*)&Shi[(mt*16 + l16)*SS + quad*8];
                sl[mt] = *(const bf8*)&Slo[(mt*16 + l16)*SS + quad*8];
            }
            #pragma unroll
            for (int nt = 0; nt < 4; ++nt) {
                const int ncol = wave*64 + nt*16 + l16;
                bf8 bh;
                #pragma unroll
                for (int j = 0; j < 8; ++j)
                    bh[j] = Ahi[(quad*8 + j)*SA + ncol];
                #pragma unroll
                for (int mt = 0; mt < 2; ++mt) {
                    f4 acc = {0.f, 0.f, 0.f, 0.f};
                    acc = __builtin_amdgcn_mfma_f32_16x16x32_bf16(sh[mt], bh, acc, 0, 0, 0);
                    acc = __builtin_amdgcn_mfma_f32_16x16x32_bf16(sl[mt], bh, acc, 0, 0, 0);
                    #pragma unroll
                    for (int i = 0; i < 4; ++i) {
                        const int row = mt*16 + quad*4 + i;
                        Ahi[row*SA + 256 + ncol] = (short)f2us(acc[i]);
                    }
                }
            }
        }
        __syncthreads();

        // main GEMM: C[32][256] = A[32][512] @ W_r
        f4 acc[2][4];
        #pragma unroll
        for (int mt = 0; mt < 2; ++mt)
            #pragma unroll
            for (int nt = 0; nt < 4; ++nt) acc[mt][nt] = (f4){0.f, 0.f, 0.f, 0.f};

        const u16* Wt = WtAll + ((size_t)r*256 + wave*64)*512;
        for (int kt = 0; kt < 16; ++kt) {
            bf8 ah[2];
            #pragma unroll
            for (int mt = 0; mt < 2; ++mt)
                ah[mt] = *(const bf8*)&Ahi[(mt*16 + l16)*SA + kt*32 + quad*8];
            #pragma unroll
            for (int nt = 0; nt < 4; ++nt) {
                const bf8 b = *(const bf8*)&Wt[(nt*16 + l16)*512 + kt*32 + quad*8];
                #pragma unroll
                for (int mt = 0; mt < 2; ++mt)
                    acc[mt][nt] = __builtin_amdgcn_mfma_f32_16x16x32_bf16(ah[mt], b, acc[mt][nt], 0, 0, 0);
            }
        }
        __syncthreads();   // all A reads complete before epilogue overwrites

        // epilogue: +bias, relu, masks, write h, column max -> g
        const float* br = (r == 0) ? bmp1 : ((r == 1) ? bmp2 : bmp3);
        #pragma unroll
        for (int nt = 0; nt < 4; ++nt) {
            const int col = wave*64 + nt*16 + l16;
            const float bias = br[col];
            float cmax = 0.f;
            #pragma unroll
            for (int mt = 0; mt < 2; ++mt) {
                #pragma unroll
                for (int i = 0; i < 4; ++i) {
                    const int row = mt*16 + quad*4 + i;
                    float v = fmaxf(acc[mt][nt][i] + bias, 0.f);
                    if (row >= NB || cntN[row] == 0) v = 0.f;
                    Ahi[row*SA + col] = (short)f2us(v);
                    cmax = fmaxf(cmax, v);
                }
            }
            cmax = fmaxf(cmax, __shfl_xor(cmax, 16));
            cmax = fmaxf(cmax, __shfl_xor(cmax, 32));
            if (quad == 0)
                G[(size_t)g*1024 + (r+1)*256 + col] = f2us(cmax);
        }
        __syncthreads();
    }
}

// ---------------------------------------------------------------------------
// Heads: 128 blocks x 16 graphs. latent hi/lo split (exact-ish).
// ---------------------------------------------------------------------------
__global__ __launch_bounds__(256) void head_kernel(
    const char* __restrict__ ws, const u16* __restrict__ G,
    const float* __restrict__ bagg, const float* __restrict__ bmu,
    const float* __restrict__ bvar, float* __restrict__ out)
{
    __shared__ __align__(16) short Lhi[16*SL];
    __shared__ __align__(16) short Llo[16*SL];

    const int tid  = threadIdx.x;
    const int wave = tid >> 6, lane = tid & 63;
    const int l16  = lane & 15, quad = lane >> 4;
    const int g0   = blockIdx.x * 16;

    const u16* WtA = (const u16*)(ws + WOFF_WAGG);
    const u16* WtM = (const u16*)(ws + WOFF_WMU);
    const u16* WtV = (const u16*)(ws + WOFF_WVAR);

    // GEMM1: latent[16][256] = G[16][1024] @ Wagg
    f4 acc[4];
    #pragma unroll
    for (int nt = 0; nt < 4; ++nt) acc[nt] = (f4){0.f, 0.f, 0.f, 0.f};

    for (int kt = 0; kt < 32; ++kt) {
        const bf8 ah = *(const bf8*)&G[(size_t)(g0 + l16)*1024 + kt*32 + quad*8];
        #pragma unroll
        for (int nt = 0; nt < 4; ++nt) {
            const bf8 b = *(const bf8*)&WtA[(size_t)(wave*64 + nt*16 + l16)*1024 + kt*32 + quad*8];
            acc[nt] = __builtin_amdgcn_mfma_f32_16x16x32_bf16(ah, b, acc[nt], 0, 0, 0);
        }
    }
    #pragma unroll
    for (int nt = 0; nt < 4; ++nt) {
        const int col = wave*64 + nt*16 + l16;
        const float bias = bagg[col];
        #pragma unroll
        for (int i = 0; i < 4; ++i) {
            const int row = quad*4 + i;
            const float v = acc[nt][i] + bias;
            const u16 hi = f2us(v);
            Lhi[row*SL + col] = (short)hi;
            Llo[row*SL + col] = (short)f2us(v - us2f(hi));
        }
    }
    __syncthreads();

    // GEMM2: mu / log_var
    f4 am[4], av[4];
    #pragma unroll
    for (int nt = 0; nt < 4; ++nt) {
        am[nt] = (f4){0.f, 0.f, 0.f, 0.f};
        av[nt] = (f4){0.f, 0.f, 0.f, 0.f};
    }
    for (int kt = 0; kt < 8; ++kt) {
        const bf8 ah = *(const bf8*)&Lhi[l16*SL + kt*32 + quad*8];
        const bf8 al = *(const bf8*)&Llo[l16*SL + kt*32 + quad*8];
        #pragma unroll
        for (int nt = 0; nt < 4; ++nt) {
            const bf8 bm_ = *(const bf8*)&WtM[(wave*64 + nt*16 + l16)*256 + kt*32 + quad*8];
            const bf8 bv_ = *(const bf8*)&WtV[(wave*64 + nt*16 + l16)*256 + kt*32 + quad*8];
            am[nt] = __builtin_amdgcn_mfma_f32_16x16x32_bf16(ah, bm_, am[nt], 0, 0, 0);
            am[nt] = __builtin_amdgcn_mfma_f32_16x16x32_bf16(al, bm_, am[nt], 0, 0, 0);
            av[nt] = __builtin_amdgcn_mfma_f32_16x16x32_bf16(ah, bv_, av[nt], 0, 0, 0);
            av[nt] = __builtin_amdgcn_mfma_f32_16x16x32_bf16(al, bv_, av[nt], 0, 0, 0);
        }
    }
    #pragma unroll
    for (int nt = 0; nt < 4; ++nt) {
        const int col = wave*64 + nt*16 + l16;
        const float b1 = bmu[col], b2 = bvar[col];
        #pragma unroll
        for (int i = 0; i < 4; ++i) {
            const int row = g0 + quad*4 + i;
            out[(size_t)row*256 + col]          = am[nt][i] + b1;
            out[524288 + (size_t)row*256 + col] = av[nt][i] + b2;
        }
    }
}

extern "C" void kernel_launch(void* const* d_in, const int* in_sizes, int n_in,
                              void* d_out, int out_size, void* d_ws, size_t ws_size,
                              hipStream_t stream)
{
    const float* geometry  = (const float*)d_in[0];
    const void*  semantic  = d_in[1];
    const void*  edge_ix   = d_in[2];
    const void*  batch     = d_in[3];
    const float* W_geo = (const float*)d_in[4];
    const float* b_geo = (const float*)d_in[5];
    const float* emb   = (const float*)d_in[6];
    const float* W_lot = (const float*)d_in[7];
    const float* b_lot = (const float*)d_in[8];
    const float* Wmp1  = (const float*)d_in[9];
    const float* bmp1  = (const float*)d_in[10];
    const float* Wmp2  = (const float*)d_in[11];
    const float* bmp2  = (const float*)d_in[12];
    const float* Wmp3  = (const float*)d_in[13];
    const float* bmp3  = (const float*)d_in[14];
    const float* Wagg  = (const float*)d_in[15];
    const float* bagg  = (const float*)d_in[16];
    const float* Wmu   = (const float*)d_in[17];
    const float* bmu   = (const float*)d_in[18];
    const float* Wvar  = (const float*)d_in[19];
    const float* bvar  = (const float*)d_in[20];

    char* ws    = (char*)d_ws;
    int*  flags = (int*)(ws + WOFF_FLAG);
    u16*  G     = (u16*)(ws + WOFF_G);

    prep_kernel<<<210, 256, 0, stream>>>(Wmp1, Wmp2, Wmp3, Wagg, Wmu, Wvar,
                                         W_geo, b_geo, emb, W_lot, b_lot,
                                         edge_ix, semantic, ws, flags);
    graph_kernel<<<BG, 256, 0, stream>>>(geometry, semantic, batch, edge_ix,
                                         bmp1, bmp2, bmp3, ws, G, flags);
    head_kernel<<<128, 256, 0, stream>>>(ws, G, bagg, bmu, bvar, (float*)d_out);
}

// Round 9
// 339.098 us; speedup vs baseline: 6.9773x; 1.1191x over previous
//
#include <hip/hip_runtime.h>

typedef unsigned short u16;
typedef __attribute__((ext_vector_type(8))) short bf8;   // 8 bf16 (4 VGPRs)
typedef __attribute__((ext_vector_type(4))) float f4;    // MFMA C/D frag
typedef __attribute__((ext_vector_type(4))) int i4;

#define NB  30
#define BG  2048
#define EPG 240
#define NEg (BG*EPG)
#define SA  264     // A row stride (shorts), K=256 + 8 pad
#define SS  40      // S row stride
#define SL  264     // latent row stride (heads)

// workspace offsets (bytes)
#define WOFF_WT    0                         // W_mp^T bf16 [3][256][512]
#define WOFF_WAGG  786432                    // W_agg^T bf16 [256][1024]
#define WOFF_WMU   (786432+524288)           // [256][256] bf16
#define WOFF_WVAR  (786432+524288+131072)
#define WOFF_TAB   (786432+524288+262144)    // fp32 tables: 12032 floats
#define WOFF_G     (WOFF_TAB + 48128)        // g bf16 [2048][1024]
#define WOFF_FLAG  (WOFF_G + 4194304)        // 2 ints

__device__ __forceinline__ float us2f(u16 u) {
    union { unsigned int i; float f; } v; v.i = ((unsigned int)u) << 16; return v.f;
}
__device__ __forceinline__ u16 f2us(float f) {
    union { float f; unsigned int u; } v; v.f = f;
    unsigned int u = v.u;
    return (u16)((u + 0x7FFFu + ((u >> 16) & 1u)) >> 16);   // RNE
}
__device__ __forceinline__ int ldidx(const void* p, long long i, int i64) {
    return i64 ? (int)((const long long*)p)[i] : ((const int*)p)[i];
}

// ---------------------------------------------------------------------------
// Prep (210 blocks): coalesced 64x64 tile transposes -> bf16, fp32 encoder
// tables, and the dtype probe (block 209).
// ---------------------------------------------------------------------------
__global__ __launch_bounds__(256) void prep_kernel(
    const float* __restrict__ Wmp1, const float* __restrict__ Wmp2,
    const float* __restrict__ Wmp3, const float* __restrict__ Wagg,
    const float* __restrict__ Wmu,  const float* __restrict__ Wvar,
    const float* __restrict__ W_geo, const float* __restrict__ b_geo,
    const float* __restrict__ emb,   const float* __restrict__ W_lot,
    const float* __restrict__ b_lot,
    const void* __restrict__ edge,  const void* __restrict__ semA,
    char* __restrict__ ws, int* __restrict__ flags)
{
    const int t = threadIdx.x;
    const int b = blockIdx.x;

    if (b == 209) {                    // probe
        if (t == 0) {
            const int* e32 = (const int*)edge;
            int zc = 0;
            for (int j = 1; j <= 31; j += 2) if (e32[j] == 0) zc++;
            const int i64 = (zc == 16) ? 1 : 0;
            flags[0] = i64;
            const int a = ldidx(semA, 61439, i64);   // semantic<=10, batch last=2047
            flags[1] = (a > 10) ? 1 : 0;
        }
        return;
    }

    if (b >= 192) {                    // tables (exact fp32 algebra)
        float* tab = (float*)(ws + WOFF_TAB);
        const int d = t, b2 = b - 192;
        if (b2 < 5) {
            float a = 0.f;
            for (int k = 0; k < 256; ++k)
                a = fmaf(W_geo[b2*256 + k], W_lot[k*256 + d], a);
            tab[b2*256 + d] = a;
        } else if (b2 < 16) {
            const int s = b2 - 5;
            float a = 0.f;
            for (int k = 0; k < 256; ++k)
                a = fmaf(emb[s*256 + k], W_lot[(256 + k)*256 + d], a);
            tab[1536 + s*256 + d] = a;
        } else {
            float a = b_lot[d];
            for (int k = 0; k < 256; ++k)
                a = fmaf(b_geo[k], W_lot[k*256 + d], a);
            tab[1280 + d] = a;
            for (int p = 0; p < NB; ++p)
                tab[4352 + p*256 + d] = W_lot[(512 + p)*256 + d];
        }
        return;
    }

    // 64x64 tile transpose: W[K][256] fp32 -> Wt[256][K] bf16
    __shared__ short tile[64 * 65];
    const float* W; u16* Wt; int K, bk, bn;
    if (b < 96)       { const int r = b/32, tt = b%32;
                        W = (r==0)?Wmp1:((r==1)?Wmp2:Wmp3);
                        Wt = (u16*)(ws + WOFF_WT) + (size_t)r*256*512;
                        K = 512;  bk = tt/4;  bn = tt%4; }
    else if (b < 160) { const int tt = b-96;
                        W = Wagg; Wt = (u16*)(ws + WOFF_WAGG);
                        K = 1024; bk = tt/4;  bn = tt%4; }
    else if (b < 176) { const int tt = b-160;
                        W = Wmu;  Wt = (u16*)(ws + WOFF_WMU);
                        K = 256;  bk = tt/4;  bn = tt%4; }
    else              { const int tt = b-176;
                        W = Wvar; Wt = (u16*)(ws + WOFF_WVAR);
                        K = 256;  bk = tt/4;  bn = tt%4; }

    const int r = t >> 6, c = t & 63;
    const int k0 = bk*64, n0 = bn*64;
    #pragma unroll
    for (int i = 0; i < 16; ++i) {
        const int kk = r + i*4;
        tile[kk*65 + c] = (short)f2us(W[(size_t)(k0 + kk)*256 + n0 + c]);
    }
    __syncthreads();
    #pragma unroll
    for (int i = 0; i < 16; ++i) {
        const int nn = r + i*4;
        Wt[(size_t)(n0 + nn)*K + k0 + c] = (u16)tile[c*65 + nn];
    }
}

// ---------------------------------------------------------------------------
// Graph kernel: one block per graph, 4 waves.
// C = h@W_top + S@(h@W_bot) + b  -- mean phase eliminated via P-fusion.
// A (= h) bf16 row-major in LDS, K=256. S exact hi/lo split.
// P fragments pass C-layout -> B-layout in-register (ds_bpermute).
// ---------------------------------------------------------------------------
__global__ __launch_bounds__(256, 4) void graph_kernel(
    const float* __restrict__ geometry,
    const void* __restrict__ semA, const void* __restrict__ semB,
    const void* __restrict__ edge_index,
    const float* __restrict__ bmp1, const float* __restrict__ bmp2,
    const float* __restrict__ bmp3,
    const char* __restrict__ ws, u16* __restrict__ G,
    const int* __restrict__ flags)
{
    __shared__ __align__(16) short Ahi[32*SA];   // 16896 B
    __shared__ __align__(16) short Shi[32*SS];   // 2560 B
    __shared__ __align__(16) short Slo[32*SS];   // 2560 B
    __shared__ int   cntC[32*32];                // 4096 B
    __shared__ int   cntN[32];
    __shared__ float geo_l[NB*5];
    __shared__ int   sem_l[NB];

    const int tid  = threadIdx.x;
    const int g    = blockIdx.x;
    const int wave = tid >> 6, lane = tid & 63;
    const int l16  = lane & 15, quad = lane >> 4;

    const int i64 = flags[0];
    const void* semantic = flags[1] ? semB : semA;
    const u16* WtAll = (const u16*)(ws + WOFF_WT);
    const float* tab = (const float*)(ws + WOFF_TAB);

    // ---- zero / stage ----
    {
        i4 z = {0, 0, 0, 0};
        if (tid < 66) ((i4*)&Ahi[30*SA])[tid] = z;            // rows 30,31
        if (tid < 160) { ((i4*)Shi)[tid] = z; ((i4*)Slo)[tid] = z; }
        ((i4*)cntC)[tid] = z;                                 // 256 i4 = 1024 ints
        if (tid < 32) cntN[tid] = 0;
        if (tid < NB*5) geo_l[tid] = geometry[(size_t)g*NB*5 + tid];
        if (tid < NB)   sem_l[tid] = ldidx(semantic, g*NB + tid, i64);
    }
    __syncthreads();

    // ---- edge counts ----
    if (tid < EPG) {
        const long long e = (long long)g*EPG + tid;
        const int s  = ldidx(edge_index, e,                  i64) - g*NB;
        const int dd = ldidx(edge_index, (long long)NEg + e, i64) - g*NB;
        atomicAdd(&cntC[dd*32 + s], 1);
        atomicAdd(&cntN[dd], 1);
    }
    __syncthreads();

    // ---- S = cnt_nm / cnt_n, exact hi/lo split ----
    for (int i = tid; i < 960; i += 256) {
        const int n = i >> 5, m = i & 31;
        const int c = cntC[n*32 + m], cn = cntN[n];
        const float v = (cn > 0) ? (float)c / (float)cn : 0.f;
        const u16 hi = f2us(v);
        Shi[n*SS + m] = (short)hi;
        Slo[n*SS + m] = (short)f2us(v - us2f(hi));
    }

    // ---- encoder via exact tables; thread = col d ----
    {
        const int d = tid;
        const float m0 = tab[0*256+d], m1 = tab[1*256+d], m2 = tab[2*256+d],
                    m3 = tab[3*256+d], m4 = tab[4*256+d];
        const float cD = tab[1280 + d];
        float gmax = 0.f;
        for (int n = 0; n < NB; ++n) {
            const int s = sem_l[n];
            float a = cD + tab[1536 + s*256 + d] + tab[4352 + n*256 + d];
            a = fmaf(geo_l[n*5+0], m0, a); a = fmaf(geo_l[n*5+1], m1, a);
            a = fmaf(geo_l[n*5+2], m2, a); a = fmaf(geo_l[n*5+3], m3, a);
            a = fmaf(geo_l[n*5+4], m4, a);
            const float v = fmaxf(a, 0.f);
            Ahi[n*SA + d] = (short)f2us(v);
            gmax = fmaxf(gmax, v);
        }
        G[(size_t)g*1024 + d] = f2us(gmax);   // g0
    }
    __syncthreads();

    // ---- per-lane row mask (8 output rows) ----
    unsigned rmask = 0;
    #pragma unroll
    for (int mt = 0; mt < 2; ++mt)
        #pragma unroll
        for (int i = 0; i < 4; ++i) {
            const int row = mt*16 + quad*4 + i;
            if (row < NB && cntN[row] > 0) rmask |= 1u << (mt*4 + i);
        }

    // S fragments (constant across rounds)
    bf8 sh[2], sl[2];
    #pragma unroll
    for (int mo = 0; mo < 2; ++mo) {
        sh[mo] = *(const bf8*)&Shi[(mo*16 + l16)*SS + quad*8];
        sl[mo] = *(const bf8*)&Slo[(mo*16 + l16)*SS + quad*8];
    }
    const int srcbase = ((quad & 1) << 5) | l16;
    const int mtsel   = quad >> 1;

    // ---- 3 message-passing rounds ----
    for (int r = 0; r < 3; ++r) {
        const u16* Wt = WtAll + ((size_t)r*256 + wave*64)*512;

        f4 C1[2][4], P[2][4];
        #pragma unroll
        for (int mt = 0; mt < 2; ++mt)
            #pragma unroll
            for (int nt = 0; nt < 4; ++nt) {
                C1[mt][nt] = (f4){0.f, 0.f, 0.f, 0.f};
                P [mt][nt] = (f4){0.f, 0.f, 0.f, 0.f};
            }

        for (int kt = 0; kt < 8; ++kt) {
            bf8 ah[2];
            #pragma unroll
            for (int mt = 0; mt < 2; ++mt)
                ah[mt] = *(const bf8*)&Ahi[(mt*16 + l16)*SA + kt*32 + quad*8];
            #pragma unroll
            for (int nt = 0; nt < 4; ++nt) {
                const u16* wrow = Wt + (size_t)(nt*16 + l16)*512 + kt*32 + quad*8;
                const bf8 bt = *(const bf8*)wrow;          // W_top (k 0..255)
                const bf8 bb = *(const bf8*)(wrow + 256);  // W_bot (k 256..511)
                #pragma unroll
                for (int mt = 0; mt < 2; ++mt) {
                    C1[mt][nt] = __builtin_amdgcn_mfma_f32_16x16x32_bf16(ah[mt], bt, C1[mt][nt], 0, 0, 0);
                    P [mt][nt] = __builtin_amdgcn_mfma_f32_16x16x32_bf16(ah[mt], bb, P [mt][nt], 0, 0, 0);
                }
            }
        }

        // pack P to bf16 pairs: pk[mt][nt][p] = rows (mt*16+quad*4+2p, +2p+1)
        unsigned pk[2][4][2];
        #pragma unroll
        for (int mt = 0; mt < 2; ++mt)
            #pragma unroll
            for (int nt = 0; nt < 4; ++nt) {
                pk[mt][nt][0] = (unsigned)f2us(P[mt][nt][0]) | ((unsigned)f2us(P[mt][nt][1]) << 16);
                pk[mt][nt][1] = (unsigned)f2us(P[mt][nt][2]) | ((unsigned)f2us(P[mt][nt][3]) << 16);
            }

        // C1 += S @ P   (B-frags built in-register via shfl)
        #pragma unroll
        for (int nt = 0; nt < 4; ++nt) {
            union { bf8 v; unsigned u[4]; } bf_;
            #pragma unroll
            for (int t = 0; t < 4; ++t) {
                const int src = srcbase + ((t >> 1) << 4);
                const unsigned v0 = __shfl(pk[0][nt][t & 1], src, 64);
                const unsigned v1 = __shfl(pk[1][nt][t & 1], src, 64);
                bf_.u[t] = mtsel ? v1 : v0;
            }
            #pragma unroll
            for (int mo = 0; mo < 2; ++mo) {
                C1[mo][nt] = __builtin_amdgcn_mfma_f32_16x16x32_bf16(sh[mo], bf_.v, C1[mo][nt], 0, 0, 0);
                C1[mo][nt] = __builtin_amdgcn_mfma_f32_16x16x32_bf16(sl[mo], bf_.v, C1[mo][nt], 0, 0, 0);
            }
        }
        __syncthreads();   // all A reads complete before epilogue overwrites

        // epilogue: +bias, relu, masks, write h, column max -> g
        const float* br = (r == 0) ? bmp1 : ((r == 1) ? bmp2 : bmp3);
        #pragma unroll
        for (int nt = 0; nt < 4; ++nt) {
            const int col = wave*64 + nt*16 + l16;
            const float bias = br[col];
            float cmax = 0.f;
            #pragma unroll
            for (int mt = 0; mt < 2; ++mt)
                #pragma unroll
                for (int i = 0; i < 4; ++i) {
                    const int row = mt*16 + quad*4 + i;
                    float v = fmaxf(C1[mt][nt][i] + bias, 0.f);
                    if (!((rmask >> (mt*4 + i)) & 1u)) v = 0.f;
                    Ahi[row*SA + col] = (short)f2us(v);
                    cmax = fmaxf(cmax, v);
                }
            cmax = fmaxf(cmax, __shfl_xor(cmax, 16, 64));
            cmax = fmaxf(cmax, __shfl_xor(cmax, 32, 64));
            if (quad == 0)
                G[(size_t)g*1024 + (r+1)*256 + col] = f2us(cmax);
        }
        __syncthreads();
    }
}

// ---------------------------------------------------------------------------
// Heads: 128 blocks x 16 graphs. latent hi/lo split.
// ---------------------------------------------------------------------------
__global__ __launch_bounds__(256) void head_kernel(
    const char* __restrict__ ws, const u16* __restrict__ G,
    const float* __restrict__ bagg, const float* __restrict__ bmu,
    const float* __restrict__ bvar, float* __restrict__ out)
{
    __shared__ __align__(16) short Lhi[16*SL];
    __shared__ __align__(16) short Llo[16*SL];

    const int tid  = threadIdx.x;
    const int wave = tid >> 6, lane = tid & 63;
    const int l16  = lane & 15, quad = lane >> 4;
    const int g0   = blockIdx.x * 16;

    const u16* WtA = (const u16*)(ws + WOFF_WAGG);
    const u16* WtM = (const u16*)(ws + WOFF_WMU);
    const u16* WtV = (const u16*)(ws + WOFF_WVAR);

    // GEMM1: latent[16][256] = G[16][1024] @ Wagg
    f4 acc[4];
    #pragma unroll
    for (int nt = 0; nt < 4; ++nt) acc[nt] = (f4){0.f, 0.f, 0.f, 0.f};

    for (int kt = 0; kt < 32; ++kt) {
        const bf8 ah = *(const bf8*)&G[(size_t)(g0 + l16)*1024 + kt*32 + quad*8];
        #pragma unroll
        for (int nt = 0; nt < 4; ++nt) {
            const bf8 b = *(const bf8*)&WtA[(size_t)(wave*64 + nt*16 + l16)*1024 + kt*32 + quad*8];
            acc[nt] = __builtin_amdgcn_mfma_f32_16x16x32_bf16(ah, b, acc[nt], 0, 0, 0);
        }
    }
    #pragma unroll
    for (int nt = 0; nt < 4; ++nt) {
        const int col = wave*64 + nt*16 + l16;
        const float bias = bagg[col];
        #pragma unroll
        for (int i = 0; i < 4; ++i) {
            const int row = quad*4 + i;
            const float v = acc[nt][i] + bias;
            const u16 hi = f2us(v);
            Lhi[row*SL + col] = (short)hi;
            Llo[row*SL + col] = (short)f2us(v - us2f(hi));
        }
    }
    __syncthreads();

    // GEMM2: mu / log_var
    f4 am[4], av[4];
    #pragma unroll
    for (int nt = 0; nt < 4; ++nt) {
        am[nt] = (f4){0.f, 0.f, 0.f, 0.f};
        av[nt] = (f4){0.f, 0.f, 0.f, 0.f};
    }
    for (int kt = 0; kt < 8; ++kt) {
        const bf8 ah = *(const bf8*)&Lhi[l16*SL + kt*32 + quad*8];
        const bf8 al = *(const bf8*)&Llo[l16*SL + kt*32 + quad*8];
        #pragma unroll
        for (int nt = 0; nt < 4; ++nt) {
            const bf8 bm_ = *(const bf8*)&WtM[(wave*64 + nt*16 + l16)*256 + kt*32 + quad*8];
            const bf8 bv_ = *(const bf8*)&WtV[(wave*64 + nt*16 + l16)*256 + kt*32 + quad*8];
            am[nt] = __builtin_amdgcn_mfma_f32_16x16x32_bf16(ah, bm_, am[nt], 0, 0, 0);
            am[nt] = __builtin_amdgcn_mfma_f32_16x16x32_bf16(al, bm_, am[nt], 0, 0, 0);
            av[nt] = __builtin_amdgcn_mfma_f32_16x16x32_bf16(ah, bv_, av[nt], 0, 0, 0);
            av[nt] = __builtin_amdgcn_mfma_f32_16x16x32_bf16(al, bv_, av[nt], 0, 0, 0);
        }
    }
    #pragma unroll
    for (int nt = 0; nt < 4; ++nt) {
        const int col = wave*64 + nt*16 + l16;
        const float b1 = bmu[col], b2 = bvar[col];
        #pragma unroll
        for (int i = 0; i < 4; ++i) {
            const int row = g0 + quad*4 + i;
            out[(size_t)row*256 + col]          = am[nt][i] + b1;
            out[524288 + (size_t)row*256 + col] = av[nt][i] + b2;
        }
    }
}

extern "C" void kernel_launch(void* const* d_in, const int* in_sizes, int n_in,
                              void* d_out, int out_size, void* d_ws, size_t ws_size,
                              hipStream_t stream)
{
    const float* geometry  = (const float*)d_in[0];
    const void*  semantic  = d_in[1];
    const void*  edge_ix   = d_in[2];
    const void*  batch     = d_in[3];
    const float* W_geo = (const float*)d_in[4];
    const float* b_geo = (const float*)d_in[5];
    const float* emb   = (const float*)d_in[6];
    const float* W_lot = (const float*)d_in[7];
    const float* b_lot = (const float*)d_in[8];
    const float* Wmp1  = (const float*)d_in[9];
    const float* bmp1  = (const float*)d_in[10];
    const float* Wmp2  = (const float*)d_in[11];
    const float* bmp2  = (const float*)d_in[12];
    const float* Wmp3  = (const float*)d_in[13];
    const float* bmp3  = (const float*)d_in[14];
    const float* Wagg  = (const float*)d_in[15];
    const float* bagg  = (const float*)d_in[16];
    const float* Wmu   = (const float*)d_in[17];
    const float* bmu   = (const float*)d_in[18];
    const float* Wvar  = (const float*)d_in[19];
    const float* bvar  = (const float*)d_in[20];

    char* ws    = (char*)d_ws;
    int*  flags = (int*)(ws + WOFF_FLAG);
    u16*  G     = (u16*)(ws + WOFF_G);

    prep_kernel<<<210, 256, 0, stream>>>(Wmp1, Wmp2, Wmp3, Wagg, Wmu, Wvar,
                                         W_geo, b_geo, emb, W_lot, b_lot,
                                         edge_ix, semantic, ws, flags);
    graph_kernel<<<BG, 256, 0, stream>>>(geometry, semantic, batch, edge_ix,
                                         bmp1, bmp2, bmp3, ws, G, flags);
    head_kernel<<<128, 256, 0, stream>>>(ws, G, bagg, bmu, bvar, (float*)d_out);
}